// Round 7
// baseline (2135.118 us; speedup 1.0000x reference)
//
#include <hip/hip_runtime.h>
#include <math.h>

#define TAN30f 0.57735026918962576f
#define SELU_SCALE 1.0507009873554805f
#define SELU_ALPHA 1.6732632423543772f

__device__ __forceinline__ float selu_f(float x) {
    return SELU_SCALE * (x > 0.0f ? x : SELU_ALPHA * expm1f(x));
}

// ---------- dense matmul: Y[N,128] = concat(X[N,FIC], P[N,3]?) @ W ----------
template<int FIC, bool HAS_POS, bool BIAS_SELU, bool ROWSCALE>
__global__ __launch_bounds__(256) void k_matmul128(
    const float* __restrict__ X, const float* __restrict__ P,
    const float* __restrict__ W, const float* __restrict__ bias,
    const float* __restrict__ rs,
    float* __restrict__ Y, int N)
{
    constexpr int ICT = FIC + (HAS_POS ? 3 : 0);
    __shared__ float xs[16][ICT + 1];
    int row0 = blockIdx.x * 16;

    for (int idx = threadIdx.x; idx < 16 * FIC; idx += 256) {
        int r = idx / FIC, c = idx % FIC;
        int gr = row0 + r;
        xs[r][c] = (gr < N) ? X[gr * FIC + c] : 0.0f;
    }
    if (HAS_POS) {
        for (int idx = threadIdx.x; idx < 16 * 3; idx += 256) {
            int r = idx / 3, c = idx % 3;
            int gr = row0 + r;
            xs[r][FIC + c] = (gr < N) ? P[gr * 3 + c] : 0.0f;
        }
    }
    __syncthreads();

    int col = threadIdx.x & 127;
    int half = threadIdx.x >> 7;
    float acc[8];
#pragma unroll
    for (int r = 0; r < 8; ++r) acc[r] = 0.0f;

#pragma unroll 4
    for (int i = 0; i < ICT; ++i) {
        float wv = W[i * 128 + col];
#pragma unroll
        for (int r = 0; r < 8; ++r)
            acc[r] = fmaf(xs[half * 8 + r][i], wv, acc[r]);
    }

    float bv = BIAS_SELU ? bias[col] : 0.0f;
#pragma unroll
    for (int r = 0; r < 8; ++r) {
        int gr = row0 + half * 8 + r;
        if (gr < N) {
            float v = acc[r];
            if (BIAS_SELU) v = selu_f(v + bv);
            if (ROWSCALE) v *= rs[gr];
            Y[gr * 128 + col] = v;
        }
    }
}

// ---------- CSR build: histogram -> scan -> scatter ----------
__global__ void k_hist(const int* __restrict__ col, int E, int* __restrict__ cnt) {
    int i = blockIdx.x * 256 + threadIdx.x;
    if (i < E) atomicAdd(&cnt[col[i]], 1);
}

__global__ void k_dinv(const int* __restrict__ cnt, float* __restrict__ dv, int n) {
    int i = blockIdx.x * 256 + threadIdx.x;
    if (i < n) dv[i] = rsqrtf((float)cnt[i] + 1.0f);  // +1 self loop
}

__global__ __launch_bounds__(256) void k_scan1(const int* __restrict__ in, int* __restrict__ out,
                                               int* __restrict__ bsum, int n) {
    __shared__ int s[256];
    int tid = threadIdx.x;
    int base = blockIdx.x * 1024 + tid * 4;
    int a[4];
#pragma unroll
    for (int k = 0; k < 4; ++k) a[k] = (base + k < n) ? in[base + k] : 0;
    int t = a[0] + a[1] + a[2] + a[3];
    s[tid] = t;
    __syncthreads();
    for (int off = 1; off < 256; off <<= 1) {
        int x = (tid >= off) ? s[tid - off] : 0;
        __syncthreads();
        s[tid] += x;
        __syncthreads();
    }
    int run = s[tid] - t;
#pragma unroll
    for (int k = 0; k < 4; ++k) {
        if (base + k < n) out[base + k] = run;
        run += a[k];
    }
    if (tid == 255) bsum[blockIdx.x] = s[255];
}

__global__ void k_scan2(int* __restrict__ bsum, int nb) {
    if (threadIdx.x == 0 && blockIdx.x == 0) {
        int run = 0;
        for (int i = 0; i < nb; ++i) { int v = bsum[i]; bsum[i] = run; run += v; }
    }
}

__global__ void k_scan3(int* __restrict__ rowptr, int* __restrict__ cur,
                        const int* __restrict__ bsum, int n, int E) {
    int i = blockIdx.x * 256 + threadIdx.x;
    if (i < n) {
        int v = rowptr[i] + bsum[i >> 10];
        rowptr[i] = v;
        cur[i] = v;
    }
    if (i == 0) rowptr[n] = E;
}

__global__ void k_scatter(const int* __restrict__ rows, const int* __restrict__ cols, int E,
                          int* __restrict__ cur, int* __restrict__ csr) {
    int e = blockIdx.x * 256 + threadIdx.x;
    if (e < E) {
        int p = atomicAdd(&cur[cols[e]], 1);
        csr[p] = rows[e];
    }
}

// ---------- CSR gather aggregation, fused self-loop + dinv + bias + selu ----------
__global__ __launch_bounds__(256) void k_gather128(
    const int* __restrict__ rowptr, const int* __restrict__ csr,
    const float* __restrict__ xws, const float* __restrict__ dv,
    const float* __restrict__ bias, float* __restrict__ out, int N)
{
    int t = blockIdx.x * 256 + threadIdx.x;
    int node = t >> 7, ch = t & 127;
    if (node >= N) return;
    int s = rowptr[node], e = rowptr[node + 1];
    float acc = xws[(size_t)node * 128 + ch];
    for (int i = s; i < e; ++i) {
        int src = csr[i];
        acc += xws[(size_t)src * 128 + ch];
    }
    float v = acc * dv[node] + bias[ch];
    out[(size_t)node * 128 + ch] = selu_f(v);
}

__global__ __launch_bounds__(256) void k_gather5(
    const int* __restrict__ rowptr, const int* __restrict__ csr,
    const float* __restrict__ xws, const float* __restrict__ dv,
    const float* __restrict__ bias, float* __restrict__ out, int N)
{
    int t = blockIdx.x * 256 + threadIdx.x;
    int node = t >> 3, ch = t & 7;
    if (node >= N || ch >= 5) return;
    int s = rowptr[node], e = rowptr[node + 1];
    float acc = xws[(size_t)node * 5 + ch];
    for (int i = s; i < e; ++i) {
        int src = csr[i];
        acc += xws[(size_t)src * 5 + ch];
    }
    out[(size_t)node * 5 + ch] = acc * dv[node] + bias[ch];
}

// ---------- onera transform; emits float4 {x,y,z, 0.5*|p|^2} ----------
__global__ void k_transform(const float* __restrict__ pos, float4* __restrict__ tp, int n) {
    int i = blockIdx.x * 256 + threadIdx.x;
    if (i < n) {
        float x = pos[i * 3 + 0], y = pos[i * 3 + 1], z = pos[i * 3 + 2];
        float nx = x - TAN30f * y;
        float f = 1.0f + (1.0f / 0.56f - 1.0f) * (y / 1.1963f);
        float X = nx * f, Y = y * f, Z = z * f;
        tp[i] = make_float4(X, Y, Z, 0.5f * (X * X + Y * Y + Z * Z));
    }
}

// ---------- brute-force knn (k=3): LDS-staged tiles, Q=2 queries/lane, ----------
// insert chain behind an explicit wave-level __any (convergent -> real
// s_cbranch, not if-convertible). s-space: s = 0.5|p|^2 - q.p, monotonic
// in d per query; d = 2s + |q|^2 recovered at epilogue.
#define KNN_TILE 512
#define KNN_Q 2
__global__ __launch_bounds__(256) void k_knn_part(
    const float4* __restrict__ tpq, int Nq,
    const float4* __restrict__ tpx, int Nx, int chunkLen,
    float* __restrict__ pd, int* __restrict__ pi)
{
    int q0 = blockIdx.x * (256 * KNN_Q) + threadIdx.x;
    int q1 = q0 + 256;
    int x0 = blockIdx.y * chunkLen;
    int x1 = min(x0 + chunkLen, Nx);

    float qx0 = 0.0f, qy0 = 0.0f, qz0 = 0.0f;
    float qx1 = 0.0f, qy1 = 0.0f, qz1 = 0.0f;
    if (q0 < Nq) { float4 t = tpq[q0]; qx0 = t.x; qy0 = t.y; qz0 = t.z; }
    if (q1 < Nq) { float4 t = tpq[q1]; qx1 = t.x; qy1 = t.y; qz1 = t.z; }
    float q2_0 = qx0 * qx0 + qy0 * qy0 + qz0 * qz0;
    float q2_1 = qx1 * qx1 + qy1 * qy1 + qz1 * qz1;

    float a0 = 3.4e38f, a1 = 3.4e38f, a2 = 3.4e38f;
    int   ai0 = 0, ai1 = 0, ai2 = 0;
    float c0 = 3.4e38f, c1 = 3.4e38f, c2 = 3.4e38f;
    int   ci0 = 0, ci1 = 0, ci2 = 0;

    __shared__ float4 pts[KNN_TILE];

    for (int base = x0; base < x1; base += KNN_TILE) {
        int cnt = min(KNN_TILE, x1 - base);
        __syncthreads();
        for (int j = threadIdx.x; j < cnt; j += 256) pts[j] = tpx[base + j];
        __syncthreads();
#pragma unroll 4
        for (int j = 0; j < cnt; ++j) {
            float4 p = pts[j];
            float s0 = fmaf(-qx0, p.x, fmaf(-qy0, p.y, fmaf(-qz0, p.z, p.w)));
            float s1 = fmaf(-qx1, p.x, fmaf(-qy1, p.y, fmaf(-qz1, p.z, p.w)));
            if (__any(s0 < a2)) {          // convergent wave-level guard
                if (s0 < a2) {
                    int id = base + j;
                    if (s0 < a1) {
                        a2 = a1; ai2 = ai1;
                        if (s0 < a0) { a1 = a0; ai1 = ai0; a0 = s0; ai0 = id; }
                        else         { a1 = s0; ai1 = id; }
                    } else { a2 = s0; ai2 = id; }
                }
            }
            if (__any(s1 < c2)) {
                if (s1 < c2) {
                    int id = base + j;
                    if (s1 < c1) {
                        c2 = c1; ci2 = ci1;
                        if (s1 < c0) { c1 = c0; ci1 = ci0; c0 = s1; ci0 = id; }
                        else         { c1 = s1; ci1 = id; }
                    } else { c2 = s1; ci2 = id; }
                }
            }
        }
    }
    if (q0 < Nq) {
        size_t o = ((size_t)blockIdx.y * Nq + q0) * 3;
        pd[o + 0] = fmaf(2.0f, a0, q2_0);
        pd[o + 1] = fmaf(2.0f, a1, q2_0);
        pd[o + 2] = fmaf(2.0f, a2, q2_0);
        pi[o + 0] = ai0; pi[o + 1] = ai1; pi[o + 2] = ai2;
    }
    if (q1 < Nq) {
        size_t o = ((size_t)blockIdx.y * Nq + q1) * 3;
        pd[o + 0] = fmaf(2.0f, c0, q2_1);
        pd[o + 1] = fmaf(2.0f, c1, q2_1);
        pd[o + 2] = fmaf(2.0f, c2, q2_1);
        pi[o + 0] = ci0; pi[o + 1] = ci1; pi[o + 2] = ci2;
    }
}

__global__ void k_knn_merge(const float* __restrict__ pd, const int* __restrict__ pi,
                            int Nq, int nchunk,
                            int* __restrict__ oidx, float* __restrict__ ow)
{
    int q = blockIdx.x * 256 + threadIdx.x;
    if (q >= Nq) return;
    size_t o = (size_t)q * 3;
    float b0 = pd[o], b1 = pd[o + 1], b2 = pd[o + 2];
    int   i0 = pi[o], i1 = pi[o + 1], i2 = pi[o + 2];
    for (int c = 1; c < nchunk; ++c) {
        size_t oc = ((size_t)c * Nq + q) * 3;
#pragma unroll 3
        for (int k = 0; k < 3; ++k) {
            float d = pd[oc + k];
            int  id = pi[oc + k];
            if (d < b2) {
                if (d < b1) {
                    b2 = b1; i2 = i1;
                    if (d < b0) { b1 = b0; i1 = i0; b0 = d; i0 = id; }
                    else        { b1 = d;  i1 = id; }
                } else { b2 = d; i2 = id; }
            }
        }
    }
    float w0 = 1.0f / fmaxf(b0, 1e-16f);
    float w1 = 1.0f / fmaxf(b1, 1e-16f);
    float w2 = 1.0f / fmaxf(b2, 1e-16f);
    float s = w0 + w1 + w2;
    oidx[q * 3 + 0] = i0; oidx[q * 3 + 1] = i1; oidx[q * 3 + 2] = i2;
    ow[q * 4 + 0] = w0; ow[q * 4 + 1] = w1; ow[q * 4 + 2] = w2; ow[q * 4 + 3] = s;
}

__global__ void k_interp(const float* __restrict__ x, const int* __restrict__ idx,
                         const float* __restrict__ w, float* __restrict__ y, int Nq) {
    int t = blockIdx.x * 256 + threadIdx.x;
    if (t >= Nq * 128) return;
    int j = t >> 7, c = t & 127;
    int i0 = idx[j * 3], i1 = idx[j * 3 + 1], i2 = idx[j * 3 + 2];
    float w0 = w[j * 4], w1 = w[j * 4 + 1], w2 = w[j * 4 + 2], s = w[j * 4 + 3];
    float num = w0 * x[i0 * 128 + c] + w1 * x[i1 * 128 + c] + w2 * x[i2 * 128 + c];
    y[j * 128 + c] = num / s;
}

// ---------- output conv matmul (OC=5), row-scaled by dinv ----------
__global__ __launch_bounds__(256) void k_matmul5(const float* __restrict__ X, const float* __restrict__ P,
                                                 const float* __restrict__ W, const float* __restrict__ rs,
                                                 float* __restrict__ Y, int N) {
    __shared__ float xs[32][132];
    __shared__ float ws[131 * 5];
    int row0 = blockIdx.x * 32;
    for (int idx = threadIdx.x; idx < 131 * 5; idx += 256) ws[idx] = W[idx];
    for (int idx = threadIdx.x; idx < 32 * 128; idx += 256) {
        int r = idx >> 7, c = idx & 127;
        xs[r][c] = X[(size_t)(row0 + r) * 128 + c];
    }
    for (int idx = threadIdx.x; idx < 32 * 3; idx += 256) {
        int r = idx / 3, c = idx % 3;
        xs[r][128 + c] = P[(row0 + r) * 3 + c];
    }
    __syncthreads();
    int r = threadIdx.x >> 3;
    int c = threadIdx.x & 7;
    if (c < 5) {
        float acc = 0.0f;
        for (int i = 0; i < 131; ++i) acc = fmaf(xs[r][i], ws[i * 5 + c], acc);
        Y[(size_t)(row0 + r) * 5 + c] = acc * rs[row0 + r];
    }
}

extern "C" void kernel_launch(void* const* d_in, const int* in_sizes, int n_in,
                              void* d_out, int out_size, void* d_ws, size_t ws_size,
                              hipStream_t stream) {
    const float* latent = (const float*)d_in[0];
    const float* pos0   = (const float*)d_in[1];
    const float* pos1   = (const float*)d_in[2];
    const float* pos2   = (const float*)d_in[3];
    const float* W_lin  = (const float*)d_in[4];
    const float* b_lin  = (const float*)d_in[5];
    const float* W0 = (const float*)d_in[6];  const float* b0 = (const float*)d_in[7];
    const float* W1 = (const float*)d_in[8];  const float* b1 = (const float*)d_in[9];
    const float* W2 = (const float*)d_in[10]; const float* b2 = (const float*)d_in[11];
    const float* W3 = (const float*)d_in[12]; const float* b3 = (const float*)d_in[13];
    const float* W4 = (const float*)d_in[14]; const float* b4 = (const float*)d_in[15];
    const int* ei0 = (const int*)d_in[16];
    const int* ei1 = (const int*)d_in[17];
    const int* ei2 = (const int*)d_in[18];
    float* out = (float*)d_out;

    const int N0 = in_sizes[1] / 3, N1 = in_sizes[2] / 3, N2 = in_sizes[3] / 3;
    const int E0 = in_sizes[16] / 2, E1 = in_sizes[17] / 2, E2 = in_sizes[18] / 2;
    const int NCHUNK = 4;

    char* wsp = (char*)d_ws;
    auto alloc = [&](size_t bytes) {
        char* p = wsp;
        wsp += (bytes + 255) & ~size_t(255);
        return p;
    };
    float*  A      = (float*)alloc((size_t)N2 * 128 * 4);
    float*  Bb     = (float*)alloc((size_t)N2 * 128 * 4);
    float4* tp0    = (float4*)alloc((size_t)N0 * 16);
    float4* tp1    = (float4*)alloc((size_t)N1 * 16);
    float4* tp2    = (float4*)alloc((size_t)N2 * 16);
    float*  dv     = (float*)alloc((size_t)N2 * 4);
    int*    cnt    = (int*)  alloc((size_t)N2 * 4);
    int*    rowptr = (int*)  alloc(((size_t)N2 + 1) * 4);
    int*    cur    = (int*)  alloc((size_t)N2 * 4);
    int*    bsum   = (int*)  alloc(4096);
    int*    csr    = (int*)  alloc((size_t)E2 * 4);
    int*    kidx   = (int*)  alloc((size_t)N2 * 3 * 4);
    float*  kw     = (float*)alloc((size_t)N2 * 4 * 4);
    float*  ppd    = (float*)alloc((size_t)NCHUNK * N2 * 3 * 4);
    int*    ppi    = (int*)  alloc((size_t)NCHUNK * N2 * 3 * 4);
    float*  xw5    = (float*)alloc((size_t)N2 * 5 * 4);

    auto cdiv = [](int a, int b) { return (a + b - 1) / b; };

    // position transforms (prepacked float4 with 0.5*|p|^2)
    k_transform<<<cdiv(N0, 256), 256, 0, stream>>>(pos0, tp0, N0);
    k_transform<<<cdiv(N1, 256), 256, 0, stream>>>(pos1, tp1, N1);
    k_transform<<<cdiv(N2, 256), 256, 0, stream>>>(pos2, tp2, N2);

    auto build_graph = [&](const int* ei, int E, int N) {
        const int* cols = ei + E;
        hipMemsetAsync(cnt, 0, (size_t)N * 4, stream);
        k_hist<<<cdiv(E, 256), 256, 0, stream>>>(cols, E, cnt);
        k_dinv<<<cdiv(N, 256), 256, 0, stream>>>(cnt, dv, N);
        int nb = cdiv(N, 1024);
        k_scan1<<<nb, 256, 0, stream>>>(cnt, rowptr, bsum, N);
        k_scan2<<<1, 64, 0, stream>>>(bsum, nb);
        k_scan3<<<cdiv(N, 256), 256, 0, stream>>>(rowptr, cur, bsum, N, E);
        k_scatter<<<cdiv(E, 256), 256, 0, stream>>>(ei, cols, E, cur, csr);
    };

    auto conv128 = [&](const float* x, const float* pos, int N,
                       const float* W, const float* b, float* xws, float* outb) {
        k_matmul128<128, true, false, true><<<cdiv(N, 16), 256, 0, stream>>>(x, pos, W, nullptr, dv, xws, N);
        k_gather128<<<cdiv(N * 128, 256), 256, 0, stream>>>(rowptr, csr, xws, dv, b, outb, N);
    };

    auto knn = [&](const float4* tpq, int Nq, const float4* tpx, int Nx) {
        int chunkLen = cdiv(Nx, NCHUNK);
        dim3 grid(cdiv(Nq, 256 * KNN_Q), NCHUNK);
        k_knn_part<<<grid, 256, 0, stream>>>(tpq, Nq, tpx, Nx, chunkLen, ppd, ppi);
        k_knn_merge<<<cdiv(Nq, 256), 256, 0, stream>>>(ppd, ppi, Nq, NCHUNK, kidx, kw);
    };

    // x = selu(latent @ W_lin + b_lin)  -> A
    k_matmul128<64, false, true, false><<<cdiv(N0, 16), 256, 0, stream>>>(latent, nullptr, W_lin, b_lin, nullptr, A, N0);

    // level 0: two convs
    build_graph(ei0, E0, N0);
    conv128(A, pos0, N0, W0, b0, Bb, A);
    conv128(A, pos0, N0, W1, b1, Bb, A);

    // pool 0 -> 1
    knn(tp1, N1, tp0, N0);
    k_interp<<<cdiv(N1 * 128, 256), 256, 0, stream>>>(A, kidx, kw, Bb, N1);

    // level 1 conv
    build_graph(ei1, E1, N1);
    conv128(Bb, pos1, N1, W2, b2, A, Bb);

    // pool 1 -> 2
    knn(tp2, N2, tp1, N1);
    k_interp<<<cdiv(N2 * 128, 256), 256, 0, stream>>>(Bb, kidx, kw, A, N2);

    // level 2 conv
    build_graph(ei2, E2, N2);
    conv128(A, pos2, N2, W3, b3, Bb, A);

    // output conv (OC=5) — reuses level-2 CSR/dinv
    k_matmul5<<<cdiv(N2, 32), 256, 0, stream>>>(A, pos2, W4, dv, xw5, N2);
    k_gather5<<<cdiv(N2 * 8, 256), 256, 0, stream>>>(rowptr, csr, xw5, dv, b4, out, N2);
}

// Round 8
// 1568.675 us; speedup vs baseline: 1.3611x; 1.3611x over previous
//
#include <hip/hip_runtime.h>
#include <math.h>

#define TAN30f 0.57735026918962576f
#define SELU_SCALE 1.0507009873554805f
#define SELU_ALPHA 1.6732632423543772f

#define MAXC 65536   // max grid cells (40^3 = 64000 <= 65536)
#define MAXG 40

__device__ __forceinline__ float selu_f(float x) {
    return SELU_SCALE * (x > 0.0f ? x : SELU_ALPHA * expm1f(x));
}

struct GP {
    float ox, oy, oz, ihx, ihy, ihz, hmin2, pad;
    int Gx, Gy, Gz, maxG;
};

// ---------- dense matmul: Y[N,128] = concat(X[N,FIC], P[N,3]?) @ W ----------
template<int FIC, bool HAS_POS, bool BIAS_SELU, bool ROWSCALE>
__global__ __launch_bounds__(256) void k_matmul128(
    const float* __restrict__ X, const float* __restrict__ P,
    const float* __restrict__ W, const float* __restrict__ bias,
    const float* __restrict__ rs,
    float* __restrict__ Y, int N)
{
    constexpr int ICT = FIC + (HAS_POS ? 3 : 0);
    __shared__ float xs[16][ICT + 1];
    int row0 = blockIdx.x * 16;

    for (int idx = threadIdx.x; idx < 16 * FIC; idx += 256) {
        int r = idx / FIC, c = idx % FIC;
        int gr = row0 + r;
        xs[r][c] = (gr < N) ? X[gr * FIC + c] : 0.0f;
    }
    if (HAS_POS) {
        for (int idx = threadIdx.x; idx < 16 * 3; idx += 256) {
            int r = idx / 3, c = idx % 3;
            int gr = row0 + r;
            xs[r][FIC + c] = (gr < N) ? P[gr * 3 + c] : 0.0f;
        }
    }
    __syncthreads();

    int col = threadIdx.x & 127;
    int half = threadIdx.x >> 7;
    float acc[8];
#pragma unroll
    for (int r = 0; r < 8; ++r) acc[r] = 0.0f;

#pragma unroll 4
    for (int i = 0; i < ICT; ++i) {
        float wv = W[i * 128 + col];
#pragma unroll
        for (int r = 0; r < 8; ++r)
            acc[r] = fmaf(xs[half * 8 + r][i], wv, acc[r]);
    }

    float bv = BIAS_SELU ? bias[col] : 0.0f;
#pragma unroll
    for (int r = 0; r < 8; ++r) {
        int gr = row0 + half * 8 + r;
        if (gr < N) {
            float v = acc[r];
            if (BIAS_SELU) v = selu_f(v + bv);
            if (ROWSCALE) v *= rs[gr];
            Y[gr * 128 + col] = v;
        }
    }
}

// ---------- shared histogram/scan/scatter machinery ----------
__global__ void k_hist(const int* __restrict__ col, int E, int* __restrict__ cnt) {
    int i = blockIdx.x * 256 + threadIdx.x;
    if (i < E) atomicAdd(&cnt[col[i]], 1);
}

__global__ void k_dinv(const int* __restrict__ cnt, float* __restrict__ dv, int n) {
    int i = blockIdx.x * 256 + threadIdx.x;
    if (i < n) dv[i] = rsqrtf((float)cnt[i] + 1.0f);  // +1 self loop
}

__global__ __launch_bounds__(256) void k_scan1(const int* __restrict__ in, int* __restrict__ out,
                                               int* __restrict__ bsum, int n) {
    __shared__ int s[256];
    int tid = threadIdx.x;
    int base = blockIdx.x * 1024 + tid * 4;
    int a[4];
#pragma unroll
    for (int k = 0; k < 4; ++k) a[k] = (base + k < n) ? in[base + k] : 0;
    int t = a[0] + a[1] + a[2] + a[3];
    s[tid] = t;
    __syncthreads();
    for (int off = 1; off < 256; off <<= 1) {
        int x = (tid >= off) ? s[tid - off] : 0;
        __syncthreads();
        s[tid] += x;
        __syncthreads();
    }
    int run = s[tid] - t;
#pragma unroll
    for (int k = 0; k < 4; ++k) {
        if (base + k < n) out[base + k] = run;
        run += a[k];
    }
    if (tid == 255) bsum[blockIdx.x] = s[255];
}

__global__ void k_scan2(int* __restrict__ bsum, int nb) {
    if (threadIdx.x == 0 && blockIdx.x == 0) {
        int run = 0;
        for (int i = 0; i < nb; ++i) { int v = bsum[i]; bsum[i] = run; run += v; }
    }
}

__global__ void k_scan3(int* __restrict__ rowptr, int* __restrict__ cur,
                        const int* __restrict__ bsum, int n, int E) {
    int i = blockIdx.x * 256 + threadIdx.x;
    if (i < n) {
        int v = rowptr[i] + bsum[i >> 10];
        rowptr[i] = v;
        cur[i] = v;
    }
    if (i == 0) rowptr[n] = E;
}

__global__ void k_scatter(const int* __restrict__ rows, const int* __restrict__ cols, int E,
                          int* __restrict__ cur, int* __restrict__ csr) {
    int e = blockIdx.x * 256 + threadIdx.x;
    if (e < E) {
        int p = atomicAdd(&cur[cols[e]], 1);
        csr[p] = rows[e];
    }
}

// ---------- CSR gather aggregation, fused self-loop + dinv + bias + selu ----------
__global__ __launch_bounds__(256) void k_gather128(
    const int* __restrict__ rowptr, const int* __restrict__ csr,
    const float* __restrict__ xws, const float* __restrict__ dv,
    const float* __restrict__ bias, float* __restrict__ out, int N)
{
    int t = blockIdx.x * 256 + threadIdx.x;
    int node = t >> 7, ch = t & 127;
    if (node >= N) return;
    int s = rowptr[node], e = rowptr[node + 1];
    float acc = xws[(size_t)node * 128 + ch];
    for (int i = s; i < e; ++i) {
        int src = csr[i];
        acc += xws[(size_t)src * 128 + ch];
    }
    float v = acc * dv[node] + bias[ch];
    out[(size_t)node * 128 + ch] = selu_f(v);
}

__global__ __launch_bounds__(256) void k_gather5(
    const int* __restrict__ rowptr, const int* __restrict__ csr,
    const float* __restrict__ xws, const float* __restrict__ dv,
    const float* __restrict__ bias, float* __restrict__ out, int N)
{
    int t = blockIdx.x * 256 + threadIdx.x;
    int node = t >> 3, ch = t & 7;
    if (node >= N || ch >= 5) return;
    int s = rowptr[node], e = rowptr[node + 1];
    float acc = xws[(size_t)node * 5 + ch];
    for (int i = s; i < e; ++i) {
        int src = csr[i];
        acc += xws[(size_t)src * 5 + ch];
    }
    out[(size_t)node * 5 + ch] = acc * dv[node] + bias[ch];
}

// ---------- onera transform; emits float4 {x,y,z, |p|^2} ----------
__global__ void k_transform(const float* __restrict__ pos, float4* __restrict__ tp, int n) {
    int i = blockIdx.x * 256 + threadIdx.x;
    if (i < n) {
        float x = pos[i * 3 + 0], y = pos[i * 3 + 1], z = pos[i * 3 + 2];
        float nx = x - TAN30f * y;
        float f = 1.0f + (1.0f / 0.56f - 1.0f) * (y / 1.1963f);
        float X = nx * f, Y = y * f, Z = z * f;
        tp[i] = make_float4(X, Y, Z, (X * X + Y * Y) + Z * Z);
    }
}

// ---------- spatial grid kNN ----------
__device__ __forceinline__ unsigned f2o(float f) {
    unsigned u = __float_as_uint(f);
    return (u & 0x80000000u) ? ~u : (u | 0x80000000u);
}
__device__ __forceinline__ float o2f(unsigned o) {
    unsigned u = (o & 0x80000000u) ? (o & 0x7fffffffu) : ~o;
    return __uint_as_float(u);
}

__global__ void k_bbox_init(unsigned* __restrict__ bb) {
    if (threadIdx.x < 3) bb[threadIdx.x] = 0xFFFFFFFFu;
    else if (threadIdx.x < 6) bb[threadIdx.x] = 0u;
}

__global__ __launch_bounds__(256) void k_bbox(const float4* __restrict__ tp, int n,
                                              unsigned* __restrict__ bb) {
    __shared__ float red[6][256];
    float mn0 = 3.4e38f, mn1 = 3.4e38f, mn2 = 3.4e38f;
    float mx0 = -3.4e38f, mx1 = -3.4e38f, mx2 = -3.4e38f;
    for (int i = blockIdx.x * 256 + threadIdx.x; i < n; i += gridDim.x * 256) {
        float4 t = tp[i];
        mn0 = fminf(mn0, t.x); mx0 = fmaxf(mx0, t.x);
        mn1 = fminf(mn1, t.y); mx1 = fmaxf(mx1, t.y);
        mn2 = fminf(mn2, t.z); mx2 = fmaxf(mx2, t.z);
    }
    int tid = threadIdx.x;
    red[0][tid] = mn0; red[1][tid] = mn1; red[2][tid] = mn2;
    red[3][tid] = mx0; red[4][tid] = mx1; red[5][tid] = mx2;
    __syncthreads();
    for (int off = 128; off > 0; off >>= 1) {
        if (tid < off) {
#pragma unroll
            for (int k = 0; k < 3; ++k) {
                red[k][tid] = fminf(red[k][tid], red[k][tid + off]);
                red[3 + k][tid] = fmaxf(red[3 + k][tid], red[3 + k][tid + off]);
            }
        }
        __syncthreads();
    }
    if (tid == 0) {
#pragma unroll
        for (int k = 0; k < 3; ++k) {
            atomicMin(&bb[k], f2o(red[k][0]));
            atomicMax(&bb[3 + k], f2o(red[3 + k][0]));
        }
    }
}

__global__ void k_gridparams(const unsigned* __restrict__ bb, int n, GP* __restrict__ gp) {
    if (threadIdx.x != 0 || blockIdx.x != 0) return;
    float mn[3], mx[3];
#pragma unroll
    for (int k = 0; k < 3; ++k) { mn[k] = o2f(bb[k]); mx[k] = o2f(bb[3 + k]); }
    float e[3], o[3];
#pragma unroll
    for (int k = 0; k < 3; ++k) {
        float ext = fmaxf(mx[k] - mn[k], 1e-6f);
        float padv = ext * 1e-4f + 1e-6f;
        o[k] = mn[k] - padv;
        e[k] = ext + 2.0f * padv;
    }
    float T = (float)n * 0.2f;  // target ~5 pts/cell
    float s = cbrtf(T / (e[0] * e[1] * e[2]));
    int G[3];
#pragma unroll
    for (int k = 0; k < 3; ++k) {
        int g = (int)ceilf(e[k] * s);
        G[k] = g < 1 ? 1 : (g > MAXG ? MAXG : g);
    }
    float h[3];
#pragma unroll
    for (int k = 0; k < 3; ++k) h[k] = e[k] / (float)G[k];
    float hmin = fminf(h[0], fminf(h[1], h[2]));
    gp->ox = o[0]; gp->oy = o[1]; gp->oz = o[2];
    gp->ihx = (float)G[0] / e[0]; gp->ihy = (float)G[1] / e[1]; gp->ihz = (float)G[2] / e[2];
    gp->hmin2 = hmin * hmin;
    gp->Gx = G[0]; gp->Gy = G[1]; gp->Gz = G[2];
    gp->maxG = max(G[0], max(G[1], G[2]));
}

__global__ void k_cellid(const float4* __restrict__ tp, int n, const GP* __restrict__ gp,
                         int* __restrict__ pcell, int* __restrict__ cnt) {
    int i = blockIdx.x * 256 + threadIdx.x;
    if (i >= n) return;
    float4 t = tp[i];
    int cx = min(max((int)((t.x - gp->ox) * gp->ihx), 0), gp->Gx - 1);
    int cy = min(max((int)((t.y - gp->oy) * gp->ihy), 0), gp->Gy - 1);
    int cz = min(max((int)((t.z - gp->oz) * gp->ihz), 0), gp->Gz - 1);
    int cid = (cz * gp->Gy + cy) * gp->Gx + cx;
    pcell[i] = cid;
    atomicAdd(&cnt[cid], 1);
}

__global__ void k_cellscatter(const float4* __restrict__ tp, int n,
                              const int* __restrict__ pcell, int* __restrict__ cur,
                              float4* __restrict__ gpts) {
    int i = blockIdx.x * 256 + threadIdx.x;
    if (i >= n) return;
    int p = atomicAdd(&cur[pcell[i]], 1);
    float4 t = tp[i];
    t.w = __int_as_float(i);
    gpts[p] = t;
}

// One query per thread: search expanding Chebyshev shells until provably done.
__global__ __launch_bounds__(256) void k_knn_grid(
    const float4* __restrict__ tpq, int Nq,
    const float4* __restrict__ gpts, const int* __restrict__ crow,
    const GP* __restrict__ gp,
    int* __restrict__ oidx, float* __restrict__ ow)
{
    int qi = blockIdx.x * 256 + threadIdx.x;
    bool active = qi < Nq;

    float ox = gp->ox, oy = gp->oy, oz = gp->oz;
    float ihx = gp->ihx, ihy = gp->ihy, ihz = gp->ihz;
    float hmin2 = gp->hmin2;
    int Gx = gp->Gx, Gy = gp->Gy, Gz = gp->Gz, maxG = gp->maxG;

    float qx = 0, qy = 0, qz = 0, q2 = 0;
    if (active) { float4 t = tpq[qi]; qx = t.x; qy = t.y; qz = t.z; q2 = t.w; }
    int cx = min(max((int)((qx - ox) * ihx), 0), Gx - 1);
    int cy = min(max((int)((qy - oy) * ihy), 0), Gy - 1);
    int cz = min(max((int)((qz - oz) * ihz), 0), Gz - 1);

    float d0 = 3.4e38f, d1 = 3.4e38f, d2 = 3.4e38f;
    int j0 = 0x7FFFFFFF, j1 = 0x7FFFFFFF, j2 = 0x7FFFFFFF;

    auto scan_cell = [&](int cell) {
        int s = crow[cell], e = crow[cell + 1];
        for (int i = s; i < e; ++i) {
            float4 p = gpts[i];
            int id = __float_as_int(p.w);
            float px2 = fmaf(p.z, p.z, fmaf(p.y, p.y, p.x * p.x));
            float dot = fmaf(p.z, qz, fmaf(p.y, qy, p.x * qx));
            float d = (q2 - 2.0f * dot) + px2;
            // lexicographic (d, id) insert — matches top_k tie order
            if (d < d2 || (d == d2 && id < j2)) {
                if (d < d1 || (d == d1 && id < j1)) {
                    d2 = d1; j2 = j1;
                    if (d < d0 || (d == d0 && id < j0)) {
                        d1 = d0; j1 = j0; d0 = d; j0 = id;
                    } else { d1 = d; j1 = id; }
                } else { d2 = d; j2 = id; }
            }
        }
    };

    if (active) {
        for (int zz = max(cz - 1, 0); zz <= min(cz + 1, Gz - 1); ++zz)
            for (int yy = max(cy - 1, 0); yy <= min(cy + 1, Gy - 1); ++yy)
                for (int xx = max(cx - 1, 0); xx <= min(cx + 1, Gx - 1); ++xx)
                    scan_cell((zz * Gy + yy) * Gx + xx);
    }
    bool done = !active || (d2 < hmin2);   // guarantee radius 1*hmin after r=1 cube

    for (int r = 2; r <= maxG; ++r) {
        if (__all(done)) break;
        if (!done) {
            for (int zz = max(cz - r, 0); zz <= min(cz + r, Gz - 1); ++zz)
                for (int yy = max(cy - r, 0); yy <= min(cy + r, Gy - 1); ++yy)
                    for (int xx = max(cx - r, 0); xx <= min(cx + r, Gx - 1); ++xx) {
                        int ch = max(max(abs(zz - cz), abs(yy - cy)), abs(xx - cx));
                        if (ch != r) continue;
                        scan_cell((zz * Gy + yy) * Gx + xx);
                    }
            done = d2 < hmin2 * (float)(r * r);
        }
    }

    if (active) {
        float w0 = 1.0f / fmaxf(d0, 1e-16f);
        float w1 = 1.0f / fmaxf(d1, 1e-16f);
        float w2 = 1.0f / fmaxf(d2, 1e-16f);
        float s = w0 + w1 + w2;
        oidx[qi * 3 + 0] = j0; oidx[qi * 3 + 1] = j1; oidx[qi * 3 + 2] = j2;
        ow[qi * 4 + 0] = w0; ow[qi * 4 + 1] = w1; ow[qi * 4 + 2] = w2; ow[qi * 4 + 3] = s;
    }
}

__global__ void k_interp(const float* __restrict__ x, const int* __restrict__ idx,
                         const float* __restrict__ w, float* __restrict__ y, int Nq) {
    int t = blockIdx.x * 256 + threadIdx.x;
    if (t >= Nq * 128) return;
    int j = t >> 7, c = t & 127;
    int i0 = idx[j * 3], i1 = idx[j * 3 + 1], i2 = idx[j * 3 + 2];
    float w0 = w[j * 4], w1 = w[j * 4 + 1], w2 = w[j * 4 + 2], s = w[j * 4 + 3];
    float num = w0 * x[i0 * 128 + c] + w1 * x[i1 * 128 + c] + w2 * x[i2 * 128 + c];
    y[j * 128 + c] = num / s;
}

// ---------- output conv matmul (OC=5), row-scaled by dinv ----------
__global__ __launch_bounds__(256) void k_matmul5(const float* __restrict__ X, const float* __restrict__ P,
                                                 const float* __restrict__ W, const float* __restrict__ rs,
                                                 float* __restrict__ Y, int N) {
    __shared__ float xs[32][132];
    __shared__ float ws[131 * 5];
    int row0 = blockIdx.x * 32;
    for (int idx = threadIdx.x; idx < 131 * 5; idx += 256) ws[idx] = W[idx];
    for (int idx = threadIdx.x; idx < 32 * 128; idx += 256) {
        int r = idx >> 7, c = idx & 127;
        xs[r][c] = X[(size_t)(row0 + r) * 128 + c];
    }
    for (int idx = threadIdx.x; idx < 32 * 3; idx += 256) {
        int r = idx / 3, c = idx % 3;
        xs[r][128 + c] = P[(row0 + r) * 3 + c];
    }
    __syncthreads();
    int r = threadIdx.x >> 3;
    int c = threadIdx.x & 7;
    if (c < 5) {
        float acc = 0.0f;
        for (int i = 0; i < 131; ++i) acc = fmaf(xs[r][i], ws[i * 5 + c], acc);
        Y[(size_t)(row0 + r) * 5 + c] = acc * rs[row0 + r];
    }
}

extern "C" void kernel_launch(void* const* d_in, const int* in_sizes, int n_in,
                              void* d_out, int out_size, void* d_ws, size_t ws_size,
                              hipStream_t stream) {
    const float* latent = (const float*)d_in[0];
    const float* pos0   = (const float*)d_in[1];
    const float* pos1   = (const float*)d_in[2];
    const float* pos2   = (const float*)d_in[3];
    const float* W_lin  = (const float*)d_in[4];
    const float* b_lin  = (const float*)d_in[5];
    const float* W0 = (const float*)d_in[6];  const float* b0 = (const float*)d_in[7];
    const float* W1 = (const float*)d_in[8];  const float* b1 = (const float*)d_in[9];
    const float* W2 = (const float*)d_in[10]; const float* b2 = (const float*)d_in[11];
    const float* W3 = (const float*)d_in[12]; const float* b3 = (const float*)d_in[13];
    const float* W4 = (const float*)d_in[14]; const float* b4 = (const float*)d_in[15];
    const int* ei0 = (const int*)d_in[16];
    const int* ei1 = (const int*)d_in[17];
    const int* ei2 = (const int*)d_in[18];
    float* out = (float*)d_out;

    const int N0 = in_sizes[1] / 3, N1 = in_sizes[2] / 3, N2 = in_sizes[3] / 3;
    const int E0 = in_sizes[16] / 2, E1 = in_sizes[17] / 2, E2 = in_sizes[18] / 2;

    char* wsp = (char*)d_ws;
    auto alloc = [&](size_t bytes) {
        char* p = wsp;
        wsp += (bytes + 255) & ~size_t(255);
        return p;
    };
    float*    A      = (float*)alloc((size_t)N2 * 128 * 4);
    float*    Bb     = (float*)alloc((size_t)N2 * 128 * 4);
    float4*   tp0    = (float4*)alloc((size_t)N0 * 16);
    float4*   tp1    = (float4*)alloc((size_t)N1 * 16);
    float4*   tp2    = (float4*)alloc((size_t)N2 * 16);
    float*    dv     = (float*)alloc((size_t)N2 * 4);
    int*      cnt    = (int*)  alloc((size_t)N2 * 4);         // >= MAXC
    int*      rowptr = (int*)  alloc(((size_t)N2 + 1) * 4);   // >= MAXC+1
    int*      cur    = (int*)  alloc((size_t)N2 * 4);
    int*      bsum   = (int*)  alloc(4096);
    int*      csr    = (int*)  alloc((size_t)E2 * 4);
    int*      kidx   = (int*)  alloc((size_t)N2 * 3 * 4);
    float*    kw     = (float*)alloc((size_t)N2 * 4 * 4);
    float*    xw5    = (float*)alloc((size_t)N2 * 5 * 4);
    unsigned* bb     = (unsigned*)alloc(64);
    GP*       gp     = (GP*)   alloc(sizeof(GP));
    int*      gcell  = (int*)  alloc((size_t)N1 * 4);         // max knn ref set = N1
    float4*   gpts   = (float4*)alloc((size_t)N1 * 16);

    auto cdiv = [](int a, int b) { return (a + b - 1) / b; };

    // position transforms (prepacked float4 with |p|^2)
    k_transform<<<cdiv(N0, 256), 256, 0, stream>>>(pos0, tp0, N0);
    k_transform<<<cdiv(N1, 256), 256, 0, stream>>>(pos1, tp1, N1);
    k_transform<<<cdiv(N2, 256), 256, 0, stream>>>(pos2, tp2, N2);

    auto build_graph = [&](const int* ei, int E, int N) {
        const int* cols = ei + E;
        hipMemsetAsync(cnt, 0, (size_t)N * 4, stream);
        k_hist<<<cdiv(E, 256), 256, 0, stream>>>(cols, E, cnt);
        k_dinv<<<cdiv(N, 256), 256, 0, stream>>>(cnt, dv, N);
        int nb = cdiv(N, 1024);
        k_scan1<<<nb, 256, 0, stream>>>(cnt, rowptr, bsum, N);
        k_scan2<<<1, 64, 0, stream>>>(bsum, nb);
        k_scan3<<<cdiv(N, 256), 256, 0, stream>>>(rowptr, cur, bsum, N, E);
        k_scatter<<<cdiv(E, 256), 256, 0, stream>>>(ei, cols, E, cur, csr);
    };

    auto conv128 = [&](const float* x, const float* pos, int N,
                       const float* W, const float* b, float* xws, float* outb) {
        k_matmul128<128, true, false, true><<<cdiv(N, 16), 256, 0, stream>>>(x, pos, W, nullptr, dv, xws, N);
        k_gather128<<<cdiv(N * 128, 256), 256, 0, stream>>>(rowptr, csr, xws, dv, b, outb, N);
    };

    // grid-accelerated knn (clobbers cnt/rowptr/cur — sequenced between graph uses)
    auto knn = [&](const float4* tpq, int Nq, const float4* tpx, int Nx) {
        k_bbox_init<<<1, 64, 0, stream>>>(bb);
        k_bbox<<<64, 256, 0, stream>>>(tpx, Nx, bb);
        k_gridparams<<<1, 1, 0, stream>>>(bb, Nx, gp);
        hipMemsetAsync(cnt, 0, (size_t)MAXC * 4, stream);
        k_cellid<<<cdiv(Nx, 256), 256, 0, stream>>>(tpx, Nx, gp, gcell, cnt);
        int nb = cdiv(MAXC, 1024);
        k_scan1<<<nb, 256, 0, stream>>>(cnt, rowptr, bsum, MAXC);
        k_scan2<<<1, 64, 0, stream>>>(bsum, nb);
        k_scan3<<<cdiv(MAXC, 256), 256, 0, stream>>>(rowptr, cur, bsum, MAXC, Nx);
        k_cellscatter<<<cdiv(Nx, 256), 256, 0, stream>>>(tpx, Nx, gcell, cur, gpts);
        k_knn_grid<<<cdiv(Nq, 256), 256, 0, stream>>>(tpq, Nq, gpts, rowptr, gp, kidx, kw);
    };

    // x = selu(latent @ W_lin + b_lin)  -> A
    k_matmul128<64, false, true, false><<<cdiv(N0, 16), 256, 0, stream>>>(latent, nullptr, W_lin, b_lin, nullptr, A, N0);

    // level 0: two convs
    build_graph(ei0, E0, N0);
    conv128(A, pos0, N0, W0, b0, Bb, A);
    conv128(A, pos0, N0, W1, b1, Bb, A);

    // pool 0 -> 1
    knn(tp1, N1, tp0, N0);
    k_interp<<<cdiv(N1 * 128, 256), 256, 0, stream>>>(A, kidx, kw, Bb, N1);

    // level 1 conv
    build_graph(ei1, E1, N1);
    conv128(Bb, pos1, N1, W2, b2, A, Bb);

    // pool 1 -> 2
    knn(tp2, N2, tp1, N1);
    k_interp<<<cdiv(N2 * 128, 256), 256, 0, stream>>>(Bb, kidx, kw, A, N2);

    // level 2 conv
    build_graph(ei2, E2, N2);
    conv128(A, pos2, N2, W3, b3, Bb, A);

    // output conv (OC=5) — reuses level-2 CSR/dinv
    k_matmul5<<<cdiv(N2, 32), 256, 0, stream>>>(A, pos2, W4, dv, xw5, N2);
    k_gather5<<<cdiv(N2 * 8, 256), 256, 0, stream>>>(rowptr, csr, xw5, dv, b4, out, N2);
}

// Round 9
// 1426.218 us; speedup vs baseline: 1.4970x; 1.0999x over previous
//
#include <hip/hip_runtime.h>
#include <math.h>

#define TAN30f 0.57735026918962576f
#define SELU_SCALE 1.0507009873554805f
#define SELU_ALPHA 1.6732632423543772f

#define MAXC 65536   // max grid cells (40^3 = 64000 <= 65536)
#define MAXG 40

__device__ __forceinline__ float selu_f(float x) {
    return SELU_SCALE * (x > 0.0f ? x : SELU_ALPHA * expm1f(x));
}

struct GP {
    float ox, oy, oz, ihx, ihy, ihz, hmin2, pad;
    int Gx, Gy, Gz, maxG;
};

// ---------- dense matmul: Y[N,128] = concat(X[N,FIC], P[N,3]?) @ W ----------
template<int FIC, bool HAS_POS, bool BIAS_SELU, bool ROWSCALE>
__global__ __launch_bounds__(256) void k_matmul128(
    const float* __restrict__ X, const float* __restrict__ P,
    const float* __restrict__ W, const float* __restrict__ bias,
    const float* __restrict__ rs,
    float* __restrict__ Y, int N)
{
    constexpr int ICT = FIC + (HAS_POS ? 3 : 0);
    __shared__ float xs[16][ICT + 1];
    int row0 = blockIdx.x * 16;

    for (int idx = threadIdx.x; idx < 16 * FIC; idx += 256) {
        int r = idx / FIC, c = idx % FIC;
        int gr = row0 + r;
        xs[r][c] = (gr < N) ? X[gr * FIC + c] : 0.0f;
    }
    if (HAS_POS) {
        for (int idx = threadIdx.x; idx < 16 * 3; idx += 256) {
            int r = idx / 3, c = idx % 3;
            int gr = row0 + r;
            xs[r][FIC + c] = (gr < N) ? P[gr * 3 + c] : 0.0f;
        }
    }
    __syncthreads();

    int col = threadIdx.x & 127;
    int half = threadIdx.x >> 7;
    float acc[8];
#pragma unroll
    for (int r = 0; r < 8; ++r) acc[r] = 0.0f;

#pragma unroll 4
    for (int i = 0; i < ICT; ++i) {
        float wv = W[i * 128 + col];
#pragma unroll
        for (int r = 0; r < 8; ++r)
            acc[r] = fmaf(xs[half * 8 + r][i], wv, acc[r]);
    }

    float bv = BIAS_SELU ? bias[col] : 0.0f;
#pragma unroll
    for (int r = 0; r < 8; ++r) {
        int gr = row0 + half * 8 + r;
        if (gr < N) {
            float v = acc[r];
            if (BIAS_SELU) v = selu_f(v + bv);
            if (ROWSCALE) v *= rs[gr];
            Y[gr * 128 + col] = v;
        }
    }
}

// ---------- shared histogram/scan/scatter machinery ----------
__global__ void k_hist(const int* __restrict__ col, int E, int* __restrict__ cnt) {
    int i = blockIdx.x * 256 + threadIdx.x;
    if (i < E) atomicAdd(&cnt[col[i]], 1);
}

__global__ void k_dinv(const int* __restrict__ cnt, float* __restrict__ dv, int n) {
    int i = blockIdx.x * 256 + threadIdx.x;
    if (i < n) dv[i] = rsqrtf((float)cnt[i] + 1.0f);  // +1 self loop
}

__global__ __launch_bounds__(256) void k_scan1(const int* __restrict__ in, int* __restrict__ out,
                                               int* __restrict__ bsum, int n) {
    __shared__ int s[256];
    int tid = threadIdx.x;
    int base = blockIdx.x * 1024 + tid * 4;
    int a[4];
#pragma unroll
    for (int k = 0; k < 4; ++k) a[k] = (base + k < n) ? in[base + k] : 0;
    int t = a[0] + a[1] + a[2] + a[3];
    s[tid] = t;
    __syncthreads();
    for (int off = 1; off < 256; off <<= 1) {
        int x = (tid >= off) ? s[tid - off] : 0;
        __syncthreads();
        s[tid] += x;
        __syncthreads();
    }
    int run = s[tid] - t;
#pragma unroll
    for (int k = 0; k < 4; ++k) {
        if (base + k < n) out[base + k] = run;
        run += a[k];
    }
    if (tid == 255) bsum[blockIdx.x] = s[255];
}

__global__ void k_scan2(int* __restrict__ bsum, int nb) {
    if (threadIdx.x == 0 && blockIdx.x == 0) {
        int run = 0;
        for (int i = 0; i < nb; ++i) { int v = bsum[i]; bsum[i] = run; run += v; }
    }
}

__global__ void k_scan3(int* __restrict__ rowptr, int* __restrict__ cur,
                        const int* __restrict__ bsum, int n, int E) {
    int i = blockIdx.x * 256 + threadIdx.x;
    if (i < n) {
        int v = rowptr[i] + bsum[i >> 10];
        rowptr[i] = v;
        cur[i] = v;
    }
    if (i == 0) rowptr[n] = E;
}

__global__ void k_scatter(const int* __restrict__ rows, const int* __restrict__ cols, int E,
                          int* __restrict__ cur, int* __restrict__ csr) {
    int e = blockIdx.x * 256 + threadIdx.x;
    if (e < E) {
        int p = atomicAdd(&cur[cols[e]], 1);
        csr[p] = rows[e];
    }
}

// ---------- CSR gather aggregation, fused self-loop + dinv + bias + selu ----------
__global__ __launch_bounds__(256) void k_gather128(
    const int* __restrict__ rowptr, const int* __restrict__ csr,
    const float* __restrict__ xws, const float* __restrict__ dv,
    const float* __restrict__ bias, float* __restrict__ out, int N)
{
    int t = blockIdx.x * 256 + threadIdx.x;
    int node = t >> 7, ch = t & 127;
    if (node >= N) return;
    int s = rowptr[node], e = rowptr[node + 1];
    float acc = xws[(size_t)node * 128 + ch];
    for (int i = s; i < e; ++i) {
        int src = csr[i];
        acc += xws[(size_t)src * 128 + ch];
    }
    float v = acc * dv[node] + bias[ch];
    out[(size_t)node * 128 + ch] = selu_f(v);
}

__global__ __launch_bounds__(256) void k_gather5(
    const int* __restrict__ rowptr, const int* __restrict__ csr,
    const float* __restrict__ xws, const float* __restrict__ dv,
    const float* __restrict__ bias, float* __restrict__ out, int N)
{
    int t = blockIdx.x * 256 + threadIdx.x;
    int node = t >> 3, ch = t & 7;
    if (node >= N || ch >= 5) return;
    int s = rowptr[node], e = rowptr[node + 1];
    float acc = xws[(size_t)node * 5 + ch];
    for (int i = s; i < e; ++i) {
        int src = csr[i];
        acc += xws[(size_t)src * 5 + ch];
    }
    out[(size_t)node * 5 + ch] = acc * dv[node] + bias[ch];
}

// ---------- onera transform; emits float4 {x,y,z, |p|^2} ----------
__global__ void k_transform(const float* __restrict__ pos, float4* __restrict__ tp, int n) {
    int i = blockIdx.x * 256 + threadIdx.x;
    if (i < n) {
        float x = pos[i * 3 + 0], y = pos[i * 3 + 1], z = pos[i * 3 + 2];
        float nx = x - TAN30f * y;
        float f = 1.0f + (1.0f / 0.56f - 1.0f) * (y / 1.1963f);
        float X = nx * f, Y = y * f, Z = z * f;
        tp[i] = make_float4(X, Y, Z, (X * X + Y * Y) + Z * Z);
    }
}

// ---------- spatial grid kNN ----------
__device__ __forceinline__ unsigned f2o(float f) {
    unsigned u = __float_as_uint(f);
    return (u & 0x80000000u) ? ~u : (u | 0x80000000u);
}
__device__ __forceinline__ float o2f(unsigned o) {
    unsigned u = (o & 0x80000000u) ? (o & 0x7fffffffu) : ~o;
    return __uint_as_float(u);
}

__global__ void k_bbox_init(unsigned* __restrict__ bb) {
    if (threadIdx.x < 3) bb[threadIdx.x] = 0xFFFFFFFFu;
    else if (threadIdx.x < 6) bb[threadIdx.x] = 0u;
}

__global__ __launch_bounds__(256) void k_bbox(const float4* __restrict__ tp, int n,
                                              unsigned* __restrict__ bb) {
    __shared__ float red[6][256];
    float mn0 = 3.4e38f, mn1 = 3.4e38f, mn2 = 3.4e38f;
    float mx0 = -3.4e38f, mx1 = -3.4e38f, mx2 = -3.4e38f;
    for (int i = blockIdx.x * 256 + threadIdx.x; i < n; i += gridDim.x * 256) {
        float4 t = tp[i];
        mn0 = fminf(mn0, t.x); mx0 = fmaxf(mx0, t.x);
        mn1 = fminf(mn1, t.y); mx1 = fmaxf(mx1, t.y);
        mn2 = fminf(mn2, t.z); mx2 = fmaxf(mx2, t.z);
    }
    int tid = threadIdx.x;
    red[0][tid] = mn0; red[1][tid] = mn1; red[2][tid] = mn2;
    red[3][tid] = mx0; red[4][tid] = mx1; red[5][tid] = mx2;
    __syncthreads();
    for (int off = 128; off > 0; off >>= 1) {
        if (tid < off) {
#pragma unroll
            for (int k = 0; k < 3; ++k) {
                red[k][tid] = fminf(red[k][tid], red[k][tid + off]);
                red[3 + k][tid] = fmaxf(red[3 + k][tid], red[3 + k][tid + off]);
            }
        }
        __syncthreads();
    }
    if (tid == 0) {
#pragma unroll
        for (int k = 0; k < 3; ++k) {
            atomicMin(&bb[k], f2o(red[k][0]));
            atomicMax(&bb[3 + k], f2o(red[3 + k][0]));
        }
    }
}

__global__ void k_gridparams(const unsigned* __restrict__ bb, int n, GP* __restrict__ gp) {
    if (threadIdx.x != 0 || blockIdx.x != 0) return;
    float mn[3], mx[3];
#pragma unroll
    for (int k = 0; k < 3; ++k) { mn[k] = o2f(bb[k]); mx[k] = o2f(bb[3 + k]); }
    float e[3], o[3];
#pragma unroll
    for (int k = 0; k < 3; ++k) {
        float ext = fmaxf(mx[k] - mn[k], 1e-6f);
        float padv = ext * 1e-4f + 1e-6f;
        o[k] = mn[k] - padv;
        e[k] = ext + 2.0f * padv;
    }
    float T = (float)n * 0.2f;  // target ~5 pts/cell
    float s = cbrtf(T / (e[0] * e[1] * e[2]));
    int G[3];
#pragma unroll
    for (int k = 0; k < 3; ++k) {
        int g = (int)ceilf(e[k] * s);
        G[k] = g < 1 ? 1 : (g > MAXG ? MAXG : g);
    }
    float h[3];
#pragma unroll
    for (int k = 0; k < 3; ++k) h[k] = e[k] / (float)G[k];
    float hmin = fminf(h[0], fminf(h[1], h[2]));
    gp->ox = o[0]; gp->oy = o[1]; gp->oz = o[2];
    gp->ihx = (float)G[0] / e[0]; gp->ihy = (float)G[1] / e[1]; gp->ihz = (float)G[2] / e[2];
    gp->hmin2 = hmin * hmin;
    gp->Gx = G[0]; gp->Gy = G[1]; gp->Gz = G[2];
    gp->maxG = max(G[0], max(G[1], G[2]));
}

__global__ void k_cellid(const float4* __restrict__ tp, int n, const GP* __restrict__ gp,
                         int* __restrict__ pcell, int* __restrict__ cnt) {
    int i = blockIdx.x * 256 + threadIdx.x;
    if (i >= n) return;
    float4 t = tp[i];
    int cx = min(max((int)((t.x - gp->ox) * gp->ihx), 0), gp->Gx - 1);
    int cy = min(max((int)((t.y - gp->oy) * gp->ihy), 0), gp->Gy - 1);
    int cz = min(max((int)((t.z - gp->oz) * gp->ihz), 0), gp->Gz - 1);
    int cid = (cz * gp->Gy + cy) * gp->Gx + cx;
    pcell[i] = cid;
    atomicAdd(&cnt[cid], 1);
}

__global__ void k_cellscatter(const float4* __restrict__ tp, int n,
                              const int* __restrict__ pcell, int* __restrict__ cur,
                              float4* __restrict__ gpts) {
    int i = blockIdx.x * 256 + threadIdx.x;
    if (i >= n) return;
    int p = atomicAdd(&cur[pcell[i]], 1);
    float4 t = tp[i];
    t.w = __int_as_float(i);
    gpts[p] = t;
}

__global__ void k_qscatter(int n, const int* __restrict__ qcell, int* __restrict__ qcur,
                           int* __restrict__ qorder) {
    int i = blockIdx.x * 256 + threadIdx.x;
    if (i >= n) return;
    int p = atomicAdd(&qcur[qcell[i]], 1);
    qorder[p] = i;
}

// Queries processed in cell-sorted order (lanes share cells -> L1-hot crow,
// cache-line-shared gpts). r=1 cube scanned as 9 x-contiguous point ranges.
__global__ __launch_bounds__(256) void k_knn_grid(
    const float4* __restrict__ tpq, int Nq, const int* __restrict__ qorder,
    const float4* __restrict__ gpts, const int* __restrict__ crow,
    const GP* __restrict__ gp,
    int* __restrict__ oidx, float* __restrict__ ow)
{
    int t = blockIdx.x * 256 + threadIdx.x;
    bool active = t < Nq;
    int qi = active ? qorder[t] : 0;

    float ox = gp->ox, oy = gp->oy, oz = gp->oz;
    float ihx = gp->ihx, ihy = gp->ihy, ihz = gp->ihz;
    float hmin2 = gp->hmin2;
    int Gx = gp->Gx, Gy = gp->Gy, Gz = gp->Gz, maxG = gp->maxG;

    float qx = 0, qy = 0, qz = 0, q2 = 0;
    if (active) { float4 tq = tpq[qi]; qx = tq.x; qy = tq.y; qz = tq.z; q2 = tq.w; }
    int cx = min(max((int)((qx - ox) * ihx), 0), Gx - 1);
    int cy = min(max((int)((qy - oy) * ihy), 0), Gy - 1);
    int cz = min(max((int)((qz - oz) * ihz), 0), Gz - 1);

    float d0 = 3.4e38f, d1 = 3.4e38f, d2 = 3.4e38f;
    int j0 = 0x7FFFFFFF, j1 = 0x7FFFFFFF, j2 = 0x7FFFFFFF;

    auto scan_range = [&](int s, int e) {
        for (int i = s; i < e; ++i) {
            float4 p = gpts[i];
            int id = __float_as_int(p.w);
            float px2 = fmaf(p.z, p.z, fmaf(p.y, p.y, p.x * p.x));
            float dot = fmaf(p.z, qz, fmaf(p.y, qy, p.x * qx));
            float d = (q2 - 2.0f * dot) + px2;
            // lexicographic (d, id) insert — matches top_k tie order
            if (d < d2 || (d == d2 && id < j2)) {
                if (d < d1 || (d == d1 && id < j1)) {
                    d2 = d1; j2 = j1;
                    if (d < d0 || (d == d0 && id < j0)) {
                        d1 = d0; j1 = j0; d0 = d; j0 = id;
                    } else { d1 = d; j1 = id; }
                } else { d2 = d; j2 = id; }
            }
        }
    };
    auto scan_cells = [&](int zz, int yy, int xlo, int xhi) {
        int base = (zz * Gy + yy) * Gx;
        scan_range(crow[base + xlo], crow[base + xhi + 1]);
    };

    if (active) {
        int xlo = max(cx - 1, 0), xhi = min(cx + 1, Gx - 1);
        for (int zz = max(cz - 1, 0); zz <= min(cz + 1, Gz - 1); ++zz)
            for (int yy = max(cy - 1, 0); yy <= min(cy + 1, Gy - 1); ++yy)
                scan_cells(zz, yy, xlo, xhi);
    }
    bool done = !active || (d2 < hmin2);   // guarantee radius 1*hmin after r=1 cube

    for (int r = 2; r <= maxG; ++r) {
        if (__all(done)) break;
        if (!done) {
            int xlo = max(cx - r, 0), xhi = min(cx + r, Gx - 1);
            for (int zz = max(cz - r, 0); zz <= min(cz + r, Gz - 1); ++zz)
                for (int yy = max(cy - r, 0); yy <= min(cy + r, Gy - 1); ++yy) {
                    if (max(abs(zz - cz), abs(yy - cy)) == r) {
                        scan_cells(zz, yy, xlo, xhi);        // full edge row
                    } else {
                        if (cx - r >= 0)      scan_cells(zz, yy, cx - r, cx - r);
                        if (cx + r <= Gx - 1) scan_cells(zz, yy, cx + r, cx + r);
                    }
                }
            done = d2 < hmin2 * (float)(r * r);
        }
    }

    if (active) {
        float w0 = 1.0f / fmaxf(d0, 1e-16f);
        float w1 = 1.0f / fmaxf(d1, 1e-16f);
        float w2 = 1.0f / fmaxf(d2, 1e-16f);
        float s = w0 + w1 + w2;
        oidx[qi * 3 + 0] = j0; oidx[qi * 3 + 1] = j1; oidx[qi * 3 + 2] = j2;
        ow[qi * 4 + 0] = w0; ow[qi * 4 + 1] = w1; ow[qi * 4 + 2] = w2; ow[qi * 4 + 3] = s;
    }
}

__global__ void k_interp(const float* __restrict__ x, const int* __restrict__ idx,
                         const float* __restrict__ w, float* __restrict__ y, int Nq) {
    int t = blockIdx.x * 256 + threadIdx.x;
    if (t >= Nq * 128) return;
    int j = t >> 7, c = t & 127;
    int i0 = idx[j * 3], i1 = idx[j * 3 + 1], i2 = idx[j * 3 + 2];
    float w0 = w[j * 4], w1 = w[j * 4 + 1], w2 = w[j * 4 + 2], s = w[j * 4 + 3];
    float num = w0 * x[i0 * 128 + c] + w1 * x[i1 * 128 + c] + w2 * x[i2 * 128 + c];
    y[j * 128 + c] = num / s;
}

// ---------- output conv matmul (OC=5), row-scaled by dinv ----------
__global__ __launch_bounds__(256) void k_matmul5(const float* __restrict__ X, const float* __restrict__ P,
                                                 const float* __restrict__ W, const float* __restrict__ rs,
                                                 float* __restrict__ Y, int N) {
    __shared__ float xs[32][132];
    __shared__ float ws[131 * 5];
    int row0 = blockIdx.x * 32;
    for (int idx = threadIdx.x; idx < 131 * 5; idx += 256) ws[idx] = W[idx];
    for (int idx = threadIdx.x; idx < 32 * 128; idx += 256) {
        int r = idx >> 7, c = idx & 127;
        xs[r][c] = X[(size_t)(row0 + r) * 128 + c];
    }
    for (int idx = threadIdx.x; idx < 32 * 3; idx += 256) {
        int r = idx / 3, c = idx % 3;
        xs[r][128 + c] = P[(row0 + r) * 3 + c];
    }
    __syncthreads();
    int r = threadIdx.x >> 3;
    int c = threadIdx.x & 7;
    if (c < 5) {
        float acc = 0.0f;
        for (int i = 0; i < 131; ++i) acc = fmaf(xs[r][i], ws[i * 5 + c], acc);
        Y[(size_t)(row0 + r) * 5 + c] = acc * rs[row0 + r];
    }
}

extern "C" void kernel_launch(void* const* d_in, const int* in_sizes, int n_in,
                              void* d_out, int out_size, void* d_ws, size_t ws_size,
                              hipStream_t stream) {
    const float* latent = (const float*)d_in[0];
    const float* pos0   = (const float*)d_in[1];
    const float* pos1   = (const float*)d_in[2];
    const float* pos2   = (const float*)d_in[3];
    const float* W_lin  = (const float*)d_in[4];
    const float* b_lin  = (const float*)d_in[5];
    const float* W0 = (const float*)d_in[6];  const float* b0 = (const float*)d_in[7];
    const float* W1 = (const float*)d_in[8];  const float* b1 = (const float*)d_in[9];
    const float* W2 = (const float*)d_in[10]; const float* b2 = (const float*)d_in[11];
    const float* W3 = (const float*)d_in[12]; const float* b3 = (const float*)d_in[13];
    const float* W4 = (const float*)d_in[14]; const float* b4 = (const float*)d_in[15];
    const int* ei0 = (const int*)d_in[16];
    const int* ei1 = (const int*)d_in[17];
    const int* ei2 = (const int*)d_in[18];
    float* out = (float*)d_out;

    const int N0 = in_sizes[1] / 3, N1 = in_sizes[2] / 3, N2 = in_sizes[3] / 3;
    const int E0 = in_sizes[16] / 2, E1 = in_sizes[17] / 2, E2 = in_sizes[18] / 2;

    char* wsp = (char*)d_ws;
    auto alloc = [&](size_t bytes) {
        char* p = wsp;
        wsp += (bytes + 255) & ~size_t(255);
        return p;
    };
    float*    A      = (float*)alloc((size_t)N2 * 128 * 4);
    float*    Bb     = (float*)alloc((size_t)N2 * 128 * 4);
    float4*   tp0    = (float4*)alloc((size_t)N0 * 16);
    float4*   tp1    = (float4*)alloc((size_t)N1 * 16);
    float4*   tp2    = (float4*)alloc((size_t)N2 * 16);
    float*    dv     = (float*)alloc((size_t)N2 * 4);
    int*      cnt    = (int*)  alloc((size_t)N2 * 4);         // >= MAXC
    int*      rowptr = (int*)  alloc(((size_t)N2 + 1) * 4);   // >= MAXC+1
    int*      cur    = (int*)  alloc((size_t)N2 * 4);
    int*      bsum   = (int*)  alloc(4096);
    int*      csr    = (int*)  alloc((size_t)E2 * 4);
    int*      kidx   = (int*)  alloc((size_t)N2 * 3 * 4);
    float*    kw     = (float*)alloc((size_t)N2 * 4 * 4);
    float*    xw5    = (float*)alloc((size_t)N2 * 5 * 4);
    unsigned* bb     = (unsigned*)alloc(64);
    GP*       gp     = (GP*)   alloc(sizeof(GP));
    int*      gcell  = (int*)  alloc((size_t)N1 * 4);         // ref cells (max ref set = N1)
    float4*   gpts   = (float4*)alloc((size_t)N1 * 16);
    int*      qcell  = (int*)  alloc((size_t)N2 * 4);         // query cells
    int*      qrow   = (int*)  alloc(((size_t)MAXC + 1) * 4);
    int*      qcur   = (int*)  alloc((size_t)MAXC * 4);
    int*      qorder = (int*)  alloc((size_t)N2 * 4);

    auto cdiv = [](int a, int b) { return (a + b - 1) / b; };

    // position transforms (prepacked float4 with |p|^2)
    k_transform<<<cdiv(N0, 256), 256, 0, stream>>>(pos0, tp0, N0);
    k_transform<<<cdiv(N1, 256), 256, 0, stream>>>(pos1, tp1, N1);
    k_transform<<<cdiv(N2, 256), 256, 0, stream>>>(pos2, tp2, N2);

    auto build_graph = [&](const int* ei, int E, int N) {
        const int* cols = ei + E;
        hipMemsetAsync(cnt, 0, (size_t)N * 4, stream);
        k_hist<<<cdiv(E, 256), 256, 0, stream>>>(cols, E, cnt);
        k_dinv<<<cdiv(N, 256), 256, 0, stream>>>(cnt, dv, N);
        int nb = cdiv(N, 1024);
        k_scan1<<<nb, 256, 0, stream>>>(cnt, rowptr, bsum, N);
        k_scan2<<<1, 64, 0, stream>>>(bsum, nb);
        k_scan3<<<cdiv(N, 256), 256, 0, stream>>>(rowptr, cur, bsum, N, E);
        k_scatter<<<cdiv(E, 256), 256, 0, stream>>>(ei, cols, E, cur, csr);
    };

    auto conv128 = [&](const float* x, const float* pos, int N,
                       const float* W, const float* b, float* xws, float* outb) {
        k_matmul128<128, true, false, true><<<cdiv(N, 16), 256, 0, stream>>>(x, pos, W, nullptr, dv, xws, N);
        k_gather128<<<cdiv(N * 128, 256), 256, 0, stream>>>(rowptr, csr, xws, dv, b, outb, N);
    };

    // grid-accelerated knn with cell-sorted queries
    // (clobbers cnt/rowptr/cur — sequenced between graph uses)
    auto knn = [&](const float4* tpq, int Nq, const float4* tpx, int Nx) {
        k_bbox_init<<<1, 64, 0, stream>>>(bb);
        k_bbox<<<64, 256, 0, stream>>>(tpx, Nx, bb);
        k_gridparams<<<1, 1, 0, stream>>>(bb, Nx, gp);
        // ref grid
        hipMemsetAsync(cnt, 0, (size_t)MAXC * 4, stream);
        k_cellid<<<cdiv(Nx, 256), 256, 0, stream>>>(tpx, Nx, gp, gcell, cnt);
        int nb = cdiv(MAXC, 1024);
        k_scan1<<<nb, 256, 0, stream>>>(cnt, rowptr, bsum, MAXC);
        k_scan2<<<1, 64, 0, stream>>>(bsum, nb);
        k_scan3<<<cdiv(MAXC, 256), 256, 0, stream>>>(rowptr, cur, bsum, MAXC, Nx);
        k_cellscatter<<<cdiv(Nx, 256), 256, 0, stream>>>(tpx, Nx, gcell, cur, gpts);
        // query sort by cell
        hipMemsetAsync(qcur, 0, (size_t)MAXC * 4, stream);
        k_cellid<<<cdiv(Nq, 256), 256, 0, stream>>>(tpq, Nq, gp, qcell, qcur);
        k_scan1<<<nb, 256, 0, stream>>>(qcur, qrow, bsum, MAXC);
        k_scan2<<<1, 64, 0, stream>>>(bsum, nb);
        k_scan3<<<cdiv(MAXC, 256), 256, 0, stream>>>(qrow, qcur, bsum, MAXC, Nq);
        k_qscatter<<<cdiv(Nq, 256), 256, 0, stream>>>(Nq, qcell, qcur, qorder);
        // search
        k_knn_grid<<<cdiv(Nq, 256), 256, 0, stream>>>(tpq, Nq, qorder, gpts, rowptr, gp, kidx, kw);
    };

    // x = selu(latent @ W_lin + b_lin)  -> A
    k_matmul128<64, false, true, false><<<cdiv(N0, 16), 256, 0, stream>>>(latent, nullptr, W_lin, b_lin, nullptr, A, N0);

    // level 0: two convs
    build_graph(ei0, E0, N0);
    conv128(A, pos0, N0, W0, b0, Bb, A);
    conv128(A, pos0, N0, W1, b1, Bb, A);

    // pool 0 -> 1
    knn(tp1, N1, tp0, N0);
    k_interp<<<cdiv(N1 * 128, 256), 256, 0, stream>>>(A, kidx, kw, Bb, N1);

    // level 1 conv
    build_graph(ei1, E1, N1);
    conv128(Bb, pos1, N1, W2, b2, A, Bb);

    // pool 1 -> 2
    knn(tp2, N2, tp1, N1);
    k_interp<<<cdiv(N2 * 128, 256), 256, 0, stream>>>(Bb, kidx, kw, A, N2);

    // level 2 conv
    build_graph(ei2, E2, N2);
    conv128(A, pos2, N2, W3, b3, Bb, A);

    // output conv (OC=5) — reuses level-2 CSR/dinv
    k_matmul5<<<cdiv(N2, 32), 256, 0, stream>>>(A, pos2, W4, dv, xw5, N2);
    k_gather5<<<cdiv(N2 * 8, 256), 256, 0, stream>>>(rowptr, csr, xw5, dv, b4, out, N2);
}